// Round 4
// baseline (272.808 us; speedup 1.0000x reference)
//
#include <hip/hip_runtime.h>

#define G_CONST     9.81f
#define DT_VEL_     0.01f
#define MAX_THRUST_ 39.96f                 // 0.9 * 44.4
#define MAX_ANGLE_  0.5235987755982988f    // 30 deg in rad
#define ALPHA_      0.16666667f            // DT/(TAU+DT) in f32
#define TILE        256

// Session model (r0-r3): CU-side read delivery pinned at 2.6-2.7 TB/s across
// LDS-staged / reg-tiled / NT structures; independent of L3-vs-HBM source mix.
// This round: single-variable probe — stage via global_load_lds (direct-to-LDS
// DMA, width=16) to test whether the cap is the TCP->VGPR return path (then
// this helps) or L2-miss/fabric delivery (then this is neutral -> roofline).

typedef __attribute__((address_space(1))) const void gconst_void;
typedef __attribute__((address_space(3))) void lds_void;

__device__ __forceinline__ void gld16(const float* g, float* l)
{
    // size must be a literal 16; lds dest must be wave-uniform (lane x 16 applied by HW)
    __builtin_amdgcn_global_load_lds((gconst_void*)g, (lds_void*)l, 16, 0, 0);
}

__device__ __forceinline__ void pid_one(
    const float* rv, const float* mv, const float* pi,
    const float* pe, const float* pd,
    float yaw, float m,
    float& rp0o, float& rp1o, float& th)
{
    const float KP[3] = {2.0f, 2.0f, 4.0f};
    const float KI[3] = {0.5f, 0.5f, 1.0f};
    const float KD[3] = {0.1f, 0.1f, 0.05f};
    float u[3];
#pragma unroll
    for (int c = 0; c < 3; ++c) {
        float err   = rv[c] - mv[c];
        float integ = pi[c] + err * DT_VEL_;
        float d_raw = (err - pe[c]) / DT_VEL_;
        float d     = pd[c] + ALPHA_ * (d_raw - pd[c]);
        float uu    = KP[c] * err + KI[c] * integ + KD[c] * d;
        u[c] = fminf(fmaxf(uu, -6.0f), 6.0f);
    }
    float s, c;
    __sincosf(yaw, &s, &c);
    float rp0 = (s * u[0] - c * u[1]) / G_CONST;
    float rp1 = (c * u[0] + s * u[1]) / G_CONST;
    float mag = sqrtf(rp0 * rp0 + rp1 * rp1);
    float sc  = fminf(MAX_ANGLE_ / (mag + 1e-6f), 1.0f);
    sc = (mag > MAX_ANGLE_) ? sc : 1.0f;
    rp0o = rp0 * sc;
    rp1o = rp1 * sc;
    th = fminf(fmaxf(m * G_CONST + m * u[2], 0.8f * G_CONST * m), MAX_THRUST_);
}

__global__ __launch_bounds__(256) void pos_ctrl_dma(
    const float* __restrict__ ref_ve,
    const float* __restrict__ meas_ve,
    const float* __restrict__ meas_yaw,
    const float* __restrict__ mass,
    const float* __restrict__ pid_int,
    const float* __restrict__ pid_prev_err,
    const float* __restrict__ pid_prev_d,
    float* __restrict__ out,   // fp32: [n*2 rp interleaved][n thrust]
    int n)
{
    // 5 x 3 KB = 15 KB LDS -> 8 blocks/CU (wave-capped)
    __shared__ float s_rv[TILE * 3];
    __shared__ float s_mv[TILE * 3];
    __shared__ float s_pi[TILE * 3];
    __shared__ float s_pe[TILE * 3];
    __shared__ float s_pd[TILE * 3];

    const int  tid  = threadIdx.x;
    const int  wid  = tid >> 6;    // wave id 0..3
    const int  lane = tid & 63;
    const long d0   = (long)blockIdx.x * TILE;

    if (d0 + TILE <= n) {
        // scalar per-drone inputs: stride-4 coalesced, normal vector loads
        const float yw = meas_yaw[d0 + tid];
        const float m  = mass[d0 + tid];

        // Stage 5 vec3 arrays via direct-to-LDS DMA.
        // Each of waves 0..2 covers 1024 B (64 lanes x 16 B) per array;
        // LDS layout is linear (lane x 16 at wave-uniform base) = r0's layout.
        if (wid < 3) {   // wave-uniform branch
            const size_t g = (size_t)d0 * 3 + ((size_t)(wid * 64 + lane) << 2); // float offset of this lane's 16B
            const int lofs = wid * 256;  // float offset of this wave's LDS segment
            gld16(ref_ve       + g, s_rv + lofs);
            gld16(meas_ve      + g, s_mv + lofs);
            gld16(pid_int      + g, s_pi + lofs);
            gld16(pid_prev_err + g, s_pe + lofs);
            gld16(pid_prev_d   + g, s_pd + lofs);
        }
        __syncthreads();   // compiler drains vmcnt (incl. global_load_lds) before barrier

        const int k = tid * 3;  // LDS read at 12B stride: <=2-way bank alias (free)
        float rp0, rp1, thr;
        pid_one(&s_rv[k], &s_mv[k], &s_pi[k], &s_pe[k], &s_pd[k],
                yw, m, rp0, rp1, thr);

        ((float2*)out)[d0 + tid] = make_float2(rp0, rp1);  // stride-8, contiguous
        out[2 * (size_t)n + d0 + tid] = thr;               // stride-4, contiguous
    } else if (d0 + tid < n) {
        // tail tile (block-uniform branch; no __syncthreads on this path)
        const long i = d0 + tid;
        const size_t k = (size_t)i * 3;
        float rp0, rp1, thr;
        pid_one(&ref_ve[k], &meas_ve[k], &pid_int[k], &pid_prev_err[k], &pid_prev_d[k],
                meas_yaw[i], mass[i], rp0, rp1, thr);
        out[(size_t)i * 2 + 0] = rp0;
        out[(size_t)i * 2 + 1] = rp1;
        out[2 * (size_t)n + i] = thr;
    }
}

extern "C" void kernel_launch(void* const* d_in, const int* in_sizes, int n_in,
                              void* d_out, int out_size, void* d_ws, size_t ws_size,
                              hipStream_t stream) {
    const float* ref_ve       = (const float*)d_in[0];
    const float* meas_ve      = (const float*)d_in[1];
    const float* meas_yaw     = (const float*)d_in[2];
    const float* mass         = (const float*)d_in[3];
    const float* pid_int      = (const float*)d_in[4];
    const float* pid_prev_err = (const float*)d_in[5];
    const float* pid_prev_d   = (const float*)d_in[6];
    float* out = (float*)d_out;
    const int n = in_sizes[2];  // meas_yaw element count == N

    const int grid = (n + TILE - 1) / TILE;
    pos_ctrl_dma<<<grid, TILE, 0, stream>>>(
        ref_ve, meas_ve, meas_yaw, mass, pid_int, pid_prev_err, pid_prev_d, out, n);
}